// Round 10
// baseline (547.138 us; speedup 1.0000x reference)
//
#include <hip/hip_runtime.h>
#include <hip/hip_bf16.h>
#include <cstdint>
#include <cstddef>

// Problem constants (fixed shapes per reference)
#define NROWS 8192
#define DIM   1024
#define BM 128
#define BN 128
#define BKB 128           // K elements (=bytes, fp8) per iteration; 8 iterations
#define EPS 1e-8f
// E pre-scaled by sqrt(10*log2(e)) so MFMA accumulates 10*log2(e)*<a,b>;
// epilogue is a bare exp2f. fp8 e4m3: input sigma ~0.12 post-scale, well
// inside the format's range; loss-error budget ~1e-3 vs 1.36e-2 threshold.
#define PRESCALE 3.798288f

typedef int    intx8   __attribute__((ext_vector_type(8)));
typedef float  floatx4 __attribute__((ext_vector_type(4)));

typedef __attribute__((address_space(1))) const void CGV;
typedef __attribute__((address_space(3))) void LV;

__device__ __forceinline__ void async_load16(const void* g, void* l) {
    __builtin_amdgcn_global_load_lds((CGV*)g, (LV*)l, 16, 0, 0);
}

// two swizzled 16B LDS chunks -> 8 consecutive K-order dwords (MFMA operand)
__device__ __forceinline__ intx8 ldfrag(const unsigned char* base, int o0, int o1) {
    int4 lo = *(const int4*)(base + o0);
    int4 hi = *(const int4*)(base + o1);
    intx8 r;
    r[0] = lo.x; r[1] = lo.y; r[2] = lo.z; r[3] = lo.w;
    r[4] = hi.x; r[5] = hi.y; r[6] = hi.z; r[7] = hi.w;
    return r;
}

// ---------------------------------------------------------------------------
// Kernel A: fp32 -> fp8 e4m3 (hardware cvt_pk, PRESCALE folded). First 64
// blocks also zero the 16384-float accumulator region.
// ---------------------------------------------------------------------------
__global__ __launch_bounds__(256) void convert_kernel(
    const float* __restrict__ in, unsigned int* __restrict__ out,
    float* __restrict__ accum /* all_sum ++ pos_sum, 2*NROWS floats */)
{
    int i = (blockIdx.x * 256 + threadIdx.x) * 4;
    float4 v = *(const float4*)(in + i);
    int p = __builtin_amdgcn_cvt_pk_fp8_f32(v.x * PRESCALE, v.y * PRESCALE, 0, false);
    p     = __builtin_amdgcn_cvt_pk_fp8_f32(v.z * PRESCALE, v.w * PRESCALE, p, true);
    out[i >> 2] = (unsigned int)p;
    if (blockIdx.x < (2 * NROWS) / 256)
        accum[blockIdx.x * 256 + threadIdx.x] = 0.0f;
}

// ---------------------------------------------------------------------------
// Kernel B: symmetric-half fused GEMM, MX-scaled FP8 (K=128, scale=1.0).
// Same proven structure as R3/R9 (global_load_lds w16, 2 barriers/iter, XOR
// chunk swizzle, XCD-local tile order) with HALF the bytes everywhere and 8
// K-iterations instead of 16. MFMA = mfma_scale_f32_16x16x128_f8f6f4 at 2x
// bf16 rate (E8M0 scale byte 127 = 1.0).
// Layouts: C/D is shape-determined (16x16: col=lane&15, row=quad*4+reg —
// epilogue identical to the verified bf16 one). A/B: m=lane&15, k=quad*32+j,
// 32 contiguous bytes/lane = 2 b128 reads at swizzled slots (2q)^swz,
// (2q+1)^swz; over a quad's 16 rows each read hits all 8 bank-groups 2-way
// (free). Off-diagonal tiles feed row- AND col-reduces; diag masks j==i.
// ---------------------------------------------------------------------------
__global__ __launch_bounds__(256, 3) void gemm_fused_kernel(
    const unsigned char* __restrict__ E,   // fp8 e4m3 (prescaled), [NROWS][DIM]
    const int*           __restrict__ labels,
    float*               __restrict__ all_sum,
    float*               __restrict__ pos_sum)
{
    __shared__ __align__(16) unsigned char sA[BM * BKB];   // 16 KB
    __shared__ __align__(16) unsigned char sB[BN * BKB];   // 16 KB

    const int tid  = threadIdx.x;
    const int lane = tid & 63;
    const int w    = tid >> 6;
    const int wm   = w >> 1;        // wave row (0..1) -> 64 rows
    const int wn   = w & 1;         // wave col (0..1) -> 64 cols
    const int colw = lane & 15;
    const int quad = lane >> 4;

    // XCD-local linear tile id, then sqrt triangle decode.
    const int b = blockIdx.x;
    const int t = (b & 7) * 260 + (b >> 3);     // 2080 = 8 x 260
    int bi = (int)((sqrtf(8.0f * (float)t + 1.0f) - 1.0f) * 0.5f);
    while ((bi + 1) * (bi + 2) / 2 <= t) ++bi;
    while (bi * (bi + 1) / 2 > t) --bi;
    const int bj = t - bi * (bi + 1) / 2;

    const int rBase = bi * BM;      // rows (A tile)
    const int cBase = bj * BN;      // cols (B tile)
    const bool diag = (bi == bj);

    // Staging: tile = 128 rows x 128 B = 1024 chunks of 16B; thread t owns
    // chunks t + 256j (rows srow + 32j). Swizzled placement: global chunk
    // c = (t&7) ^ (srow&7); srow&7 invariant under +32.
    const int srow = tid >> 3;
    const int scol = (((tid & 7) ^ (srow & 7)) << 4);  // byte col 0..112
    const int e0   = tid * 16;                         // LDS byte offset chunk0

    floatx4 acc[4][4];
    #pragma unroll
    for (int i = 0; i < 4; ++i)
        #pragma unroll
        for (int j = 0; j < 4; ++j)
            acc[i][j] = (floatx4)0.0f;

    // Fragment reads: row = {wm,wn}*64 + mt*16 + colw; lane's K-segment is
    // chunks 2q, 2q+1 stored at slots ^(row&7) = ^(colw&7).
    const int swz  = colw & 7;
    const int c0   = (((quad << 1)    ) ^ swz) << 4;
    const int c1   = (((quad << 1) | 1) ^ swz) << 4;
    const int aRow0 = (wm * 64 + colw) * BKB;
    const int bRow0 = (wn * 64 + colw) * BKB;

    const size_t gA0 = (size_t)(rBase + srow) * DIM + scol;
    const size_t gB0 = (size_t)(cBase + srow) * DIM + scol;
    const size_t rstep = (size_t)32 * DIM;

    for (int k0 = 0; k0 < DIM; k0 += BKB) {
        __syncthreads();   // previous compute done before overwrite
        async_load16(E + gA0 + k0,             &sA[e0]);
        async_load16(E + gA0 + rstep + k0,     &sA[e0 + 4096]);
        async_load16(E + gA0 + 2 * rstep + k0, &sA[e0 + 8192]);
        async_load16(E + gA0 + 3 * rstep + k0, &sA[e0 + 12288]);
        async_load16(E + gB0 + k0,             &sB[e0]);
        async_load16(E + gB0 + rstep + k0,     &sB[e0 + 4096]);
        async_load16(E + gB0 + 2 * rstep + k0, &sB[e0 + 8192]);
        async_load16(E + gB0 + 3 * rstep + k0, &sB[e0 + 12288]);
        __syncthreads();   // vmcnt drained by compiler before barrier

        intx8 aF[4];
        #pragma unroll
        for (int mt = 0; mt < 4; ++mt)
            aF[mt] = ldfrag(&sA[aRow0 + mt * 16 * BKB], c0, c1);

        #pragma unroll
        for (int nt = 0; nt < 4; ++nt) {
            intx8 bF = ldfrag(&sB[bRow0 + nt * 16 * BKB], c0, c1);
            #pragma unroll
            for (int mt = 0; mt < 4; ++mt)
                acc[mt][nt] = __builtin_amdgcn_mfma_scale_f32_16x16x128_f8f6f4(
                    aF[mt], bF, acc[mt][nt],
                    0, 0,          // cbsz=0 (A fp8 e4m3), blgp=0 (B fp8 e4m3)
                    0, 127,        // opsel_a, scale_a = E8M0 127 -> 1.0
                    0, 127);       // opsel_b, scale_b
        }
    }

    // Epilogue. C/D layout (16x16, shape-determined): col=lane&15, row=quad*4+reg.
    float labc[4];
    int   gcol[4];
    #pragma unroll
    for (int nt = 0; nt < 4; ++nt) {
        gcol[nt] = cBase + wn * 64 + nt * 16 + colw;
        labc[nt] = (float)labels[gcol[nt]];
    }

    float colAll[4] = {0.f, 0.f, 0.f, 0.f};
    float colPos[4] = {0.f, 0.f, 0.f, 0.f};

    #pragma unroll
    for (int mt = 0; mt < 4; ++mt) {
        const int growBase = rBase + wm * 64 + mt * 16 + quad * 4;
        #pragma unroll
        for (int r = 0; r < 4; ++r) {
            const int grow = growBase + r;
            const float labr = (float)labels[grow];
            float sAll = 0.f, sPos = 0.f;
            #pragma unroll
            for (int nt = 0; nt < 4; ++nt) {
                float ev = exp2f(acc[mt][nt][r]);   // PRESCALE folded into E
                if (diag && grow == gcol[nt]) ev = 0.0f;  // exclude self
                sAll += ev;
                sPos += ev * labc[nt];
                colAll[nt] += ev;
                colPos[nt] += ev * labr;
            }
            // row-reduce across the 16 lanes (same quad) sharing this row
            #pragma unroll
            for (int off = 1; off < 16; off <<= 1) {
                sAll += __shfl_xor(sAll, off);
                sPos += __shfl_xor(sPos, off);
            }
            if (colw == 0) {
                atomicAdd(&all_sum[grow], sAll);
                atomicAdd(&pos_sum[grow], sPos);
            }
        }
    }

    if (!diag) {
        // col-reduce: sum across quads (lanes differing in bits 4,5)
        #pragma unroll
        for (int nt = 0; nt < 4; ++nt) {
            float a = colAll[nt], p = colPos[nt];
            a += __shfl_xor(a, 16);  p += __shfl_xor(p, 16);
            a += __shfl_xor(a, 32);  p += __shfl_xor(p, 32);
            if (quad == 0) {
                atomicAdd(&all_sum[gcol[nt]], a);
                atomicAdd(&pos_sum[gcol[nt]], p);
            }
        }
    }
}

// ---------------------------------------------------------------------------
// Kernel C: loss = mean over rows with lab==1 of -log(pos/(all+eps)); 0 if n_ref<2
// ---------------------------------------------------------------------------
__global__ __launch_bounds__(1024) void finalize_kernel(
    const float* __restrict__ all_sum,
    const float* __restrict__ pos_sum,
    const int*   __restrict__ labels,
    float*       __restrict__ out)
{
    __shared__ float sSum[1024];
    __shared__ float sCnt[1024];
    const int tid = threadIdx.x;
    float lsum = 0.f, lcnt = 0.f;
    for (int i = tid; i < NROWS; i += 1024) {
        if (labels[i] > 0) {
            float p = pos_sum[i];
            float a = all_sum[i] + EPS;
            lsum += -logf(p / a);
            lcnt += 1.0f;
        }
    }
    sSum[tid] = lsum;
    sCnt[tid] = lcnt;
    __syncthreads();
    for (int s = 512; s > 0; s >>= 1) {
        if (tid < s) { sSum[tid] += sSum[tid + s]; sCnt[tid] += sCnt[tid + s]; }
        __syncthreads();
    }
    if (tid == 0) {
        float n = sCnt[0];
        out[0] = (n < 2.0f) ? 0.0f : sSum[0] / fmaxf(n, 1.0f);
    }
}

// ---------------------------------------------------------------------------
extern "C" void kernel_launch(void* const* d_in, const int* in_sizes, int n_in,
                              void* d_out, int out_size, void* d_ws, size_t ws_size,
                              hipStream_t stream) {
    const float* emb    = (const float*)d_in[0];
    const int*   labels = (const int*)d_in[1];
    float*       out    = (float*)d_out;

    // workspace layout: [fp8 E: 8 MB][all_sum: 32 KB][pos_sum: 32 KB]
    unsigned char* Efp8 = (unsigned char*)d_ws;
    const size_t embBytes = (size_t)NROWS * DIM;   // 1 B/elem
    float* all_sum = (float*)((char*)d_ws + embBytes);
    float* pos_sum = all_sum + NROWS;

    convert_kernel<<<(NROWS * DIM) / (4 * 256), 256, 0, stream>>>(
        emb, (unsigned int*)Efp8, all_sum);

    const int nBlocksTri = (NROWS / BM) * (NROWS / BM + 1) / 2;  // 64*65/2 = 2080
    gemm_fused_kernel<<<nBlocksTri, 256, 0, stream>>>(Efp8, labels, all_sum, pos_sum);

    finalize_kernel<<<1, 1024, 0, stream>>>(all_sum, pos_sum, labels, out);
}

// Round 11
// 186.002 us; speedup vs baseline: 2.9416x; 2.9416x over previous
//
#include <hip/hip_runtime.h>
#include <hip/hip_bf16.h>
#include <cstdint>
#include <cstddef>

// Problem constants (fixed shapes per reference)
#define NROWS 8192
#define DIM   1024
#define BMR 256           // block rows (4 waves x 64)
#define BNC 128           // block cols
#define BK  64            // K depth per iteration; 16 iterations
#define NBLK 1056         // sum over I<32 of (2I+2) = 8 XCDs x 132
#define EPS 1e-8f
// E pre-scaled by sqrt(10*log2(e)) so MFMA accumulates 10*log2(e)*<a,b>;
// epilogue is a bare exp2f.
#define PRESCALE 3.798288f

typedef short  bf16x8  __attribute__((ext_vector_type(8)));
typedef float  floatx4 __attribute__((ext_vector_type(4)));

typedef __attribute__((address_space(1))) const void CGV;
typedef __attribute__((address_space(3))) void LV;

__device__ __forceinline__ void async_load16(const void* g, void* l) {
    __builtin_amdgcn_global_load_lds((CGV*)g, (LV*)l, 16, 0, 0);
}

__device__ __forceinline__ unsigned short f2bf_rne(float f) {
    union { float f; unsigned u; } c; c.f = f;
    unsigned u = c.u;
    unsigned r = (u + 0x7fffu + ((u >> 16) & 1u)) >> 16;
    return (unsigned short)r;
}

// ---------------------------------------------------------------------------
// Kernel A: fp32 -> bf16 (RNE) with PRESCALE folded in. First 64 blocks also
// zero the 16384-float accumulator region.
// ---------------------------------------------------------------------------
__global__ __launch_bounds__(256) void convert_kernel(
    const float* __restrict__ in, unsigned short* __restrict__ out,
    float* __restrict__ accum /* all_sum ++ pos_sum, 2*NROWS floats */)
{
    int i = (blockIdx.x * 256 + threadIdx.x) * 4;
    float4 v = *(const float4*)(in + i);
    ushort4 o;
    o.x = f2bf_rne(v.x * PRESCALE);
    o.y = f2bf_rne(v.y * PRESCALE);
    o.z = f2bf_rne(v.z * PRESCALE);
    o.w = f2bf_rne(v.w * PRESCALE);
    *(ushort4*)(out + i) = o;
    if (blockIdx.x < (2 * NROWS) / 256)
        accum[blockIdx.x * 256 + threadIdx.x] = 0.0f;
}

// ---------------------------------------------------------------------------
// Kernel B: symmetric-half fused GEMM, FAT-TILE variant.
// Evidence (R3/R7/R9): kernel is LDS-READ-BANDWIDTH bound — 16 KB LDS reads
// per 155 MFMA-cycles per wave-iter predicts MfmaUtil 20% = measured. Fix:
// wave computes 64x128 (acc 4x8): 24 KB reads per 310 MFMA-cycles (1.33x
// fewer LDS bytes/MFMA); staging bytes/output and barrier count/output also
// drop. Block = 256x128, 1056 blocks (I<32 strips of 256 rows, J<=2I+1 col
// strips of 128).
// UNIFORM symmetry: keep strictly-lower elements only (grow > gcol); each
// contributes to BOTH row grow (weight lab[gcol]) and col gcol (weight
// lab[grow]) — covers every unordered pair exactly once, no diag cases.
// Fully-upper wave-tiles (2 per straddling block) early-return.
// K-loop: R3-proven global_load_lds w16 + 2 __syncthreads; chunk swizzle
// c' = c ^ (row&7) (0 conflicts measured). XCD-local tile order (R9).
// ---------------------------------------------------------------------------
__global__ __launch_bounds__(256, 2) void gemm_fused_kernel(
    const unsigned short* __restrict__ E,   // bf16 bits (prescaled), [NROWS][DIM]
    const int*            __restrict__ labels,
    float*                __restrict__ all_sum,
    float*                __restrict__ pos_sum)
{
    __shared__ __align__(16) unsigned short sA[BMR * BK];   // 32 KB
    __shared__ __align__(16) unsigned short sB[BNC * BK];   // 16 KB

    const int tid  = threadIdx.x;
    const int lane = tid & 63;
    const int w    = tid >> 6;      // wave -> rows w*64..w*64+63 of the block
    const int colw = lane & 15;
    const int quad = lane >> 4;

    // XCD-local linear tile id, then triangle decode over (I: 32 row-strips
    // of 256, J <= 2I+1 col-strips of 128). cum(I) = I*(I+1).
    const int b = blockIdx.x;
    const int t = (b & 7) * 132 + (b >> 3);     // 1056 = 8 x 132
    int I = (int)((sqrtf(4.0f * (float)t + 1.0f) - 1.0f) * 0.5f);
    while ((I + 1) * (I + 2) <= t) ++I;
    while (I * (I + 1) > t) --I;
    const int J = t - I * (I + 1);

    const int rBase = I * BMR;      // rows (A tile)
    const int cBase = J * BNC;      // cols (B tile)

    // Staging: A = 256x64 elems = 2048 chunks of 16B (8 passes of 256);
    // B = 128x64 = 1024 chunks (4 passes). Thread t stages chunk (t&7)^swz of
    // row srow+32j. Swizzle invariant under row += 32.
    const int srow = tid >> 3;                          // 0..31
    const int scol = (((tid & 7) ^ (srow & 7)) << 3);   // elem col 0..56
    const int e0   = tid * 8;                           // LDS elem offset/pass

    floatx4 acc[4][8];
    #pragma unroll
    for (int i = 0; i < 4; ++i)
        #pragma unroll
        for (int j = 0; j < 8; ++j)
            acc[i][j] = (floatx4)0.0f;

    // Fragment reads: A row = w*64 + mt*16 + colw; B row = nt*16 + colw.
    // Chunk (h*4+quad) stored at slot ^(row&7) = ^(colw&7).
    const int swz   = colw & 7;
    const int aRow0 = (w * 64 + colw) * BK;
    const int bRow0 = colw * BK;

    const size_t gA0 = (size_t)(rBase + srow) * DIM + scol;
    const size_t gB0 = (size_t)(cBase + srow) * DIM + scol;
    const size_t rstep = (size_t)32 * DIM;

    for (int k0 = 0; k0 < DIM; k0 += BK) {
        __syncthreads();   // previous compute done before overwrite
        #pragma unroll
        for (int j = 0; j < 8; ++j)
            async_load16(E + gA0 + j * rstep + k0, &sA[e0 + j * 2048]);
        #pragma unroll
        for (int j = 0; j < 4; ++j)
            async_load16(E + gB0 + j * rstep + k0, &sB[e0 + j * 2048]);
        __syncthreads();   // vmcnt drained by compiler before barrier

        #pragma unroll
        for (int h = 0; h < 2; ++h) {
            const int cOff = (((h << 2) | quad) ^ swz) << 3;
            bf16x8 aF[4], bF[8];
            #pragma unroll
            for (int mt = 0; mt < 4; ++mt)
                aF[mt] = *(const bf16x8*)&sA[aRow0 + mt * 16 * BK + cOff];
            #pragma unroll
            for (int nt = 0; nt < 8; ++nt)
                bF[nt] = *(const bf16x8*)&sB[bRow0 + nt * 16 * BK + cOff];

            #pragma unroll
            for (int mt = 0; mt < 4; ++mt)
                #pragma unroll
                for (int nt = 0; nt < 8; ++nt)
                    acc[mt][nt] = __builtin_amdgcn_mfma_f32_16x16x32_bf16(
                        aF[mt], bF[nt], acc[mt][nt], 0, 0, 0);
        }
    }

    // Fully-upper wave tile (max row < min col): nothing to contribute.
    if (rBase + w * 64 + 63 < cBase) return;

    // Epilogue. C/D layout (16x16x32): col = lane&15, row = quad*4 + reg.
    // Uniform rule: element (grow, gcol) counts iff grow > gcol; contributes
    // to row grow AND col gcol.
    float labc[8];
    int   gcol[8];
    #pragma unroll
    for (int nt = 0; nt < 8; ++nt) {
        gcol[nt] = cBase + nt * 16 + colw;
        labc[nt] = (float)labels[gcol[nt]];
    }

    float colAll[8] = {0.f, 0.f, 0.f, 0.f, 0.f, 0.f, 0.f, 0.f};
    float colPos[8] = {0.f, 0.f, 0.f, 0.f, 0.f, 0.f, 0.f, 0.f};

    #pragma unroll
    for (int mt = 0; mt < 4; ++mt) {
        const int growBase = rBase + w * 64 + mt * 16 + quad * 4;
        #pragma unroll
        for (int r = 0; r < 4; ++r) {
            const int grow = growBase + r;
            const float labr = (float)labels[grow];
            float sAll = 0.f, sPos = 0.f;
            #pragma unroll
            for (int nt = 0; nt < 8; ++nt) {
                float ev = exp2f(acc[mt][nt][r]);   // PRESCALE folded into E
                ev = (grow > gcol[nt]) ? ev : 0.0f; // strictly-lower only
                sAll += ev;
                sPos += ev * labc[nt];
                colAll[nt] += ev;
                colPos[nt] += ev * labr;
            }
            // row-reduce across the 16 lanes (same quad) sharing this row
            #pragma unroll
            for (int off = 1; off < 16; off <<= 1) {
                sAll += __shfl_xor(sAll, off);
                sPos += __shfl_xor(sPos, off);
            }
            if (colw == 0 && sAll != 0.f) {
                atomicAdd(&all_sum[grow], sAll);
                atomicAdd(&pos_sum[grow], sPos);
            }
        }
    }

    // col-reduce: sum across quads (lanes differing in bits 4,5)
    #pragma unroll
    for (int nt = 0; nt < 8; ++nt) {
        float a = colAll[nt], p = colPos[nt];
        a += __shfl_xor(a, 16);  p += __shfl_xor(p, 16);
        a += __shfl_xor(a, 32);  p += __shfl_xor(p, 32);
        if (quad == 0 && a != 0.f) {
            atomicAdd(&all_sum[gcol[nt]], a);
            atomicAdd(&pos_sum[gcol[nt]], p);
        }
    }
}

// ---------------------------------------------------------------------------
// Kernel C: loss = mean over rows with lab==1 of -log(pos/(all+eps)); 0 if n_ref<2
// ---------------------------------------------------------------------------
__global__ __launch_bounds__(1024) void finalize_kernel(
    const float* __restrict__ all_sum,
    const float* __restrict__ pos_sum,
    const int*   __restrict__ labels,
    float*       __restrict__ out)
{
    __shared__ float sSum[1024];
    __shared__ float sCnt[1024];
    const int tid = threadIdx.x;
    float lsum = 0.f, lcnt = 0.f;
    for (int i = tid; i < NROWS; i += 1024) {
        if (labels[i] > 0) {
            float p = pos_sum[i];
            float a = all_sum[i] + EPS;
            lsum += -logf(p / a);
            lcnt += 1.0f;
        }
    }
    sSum[tid] = lsum;
    sCnt[tid] = lcnt;
    __syncthreads();
    for (int s = 512; s > 0; s >>= 1) {
        if (tid < s) { sSum[tid] += sSum[tid + s]; sCnt[tid] += sCnt[tid + s]; }
        __syncthreads();
    }
    if (tid == 0) {
        float n = sCnt[0];
        out[0] = (n < 2.0f) ? 0.0f : sSum[0] / fmaxf(n, 1.0f);
    }
}

// ---------------------------------------------------------------------------
extern "C" void kernel_launch(void* const* d_in, const int* in_sizes, int n_in,
                              void* d_out, int out_size, void* d_ws, size_t ws_size,
                              hipStream_t stream) {
    const float* emb    = (const float*)d_in[0];
    const int*   labels = (const int*)d_in[1];
    float*       out    = (float*)d_out;

    // workspace layout: [bf16 E: 16 MB][all_sum: 32 KB][pos_sum: 32 KB]
    unsigned short* Ebf = (unsigned short*)d_ws;
    const size_t embBytes = (size_t)NROWS * DIM * sizeof(unsigned short);
    float* all_sum = (float*)((char*)d_ws + embBytes);
    float* pos_sum = all_sum + NROWS;

    convert_kernel<<<(NROWS * DIM) / (4 * 256), 256, 0, stream>>>(emb, Ebf, all_sum);

    gemm_fused_kernel<<<NBLK, 256, 0, stream>>>(Ebf, labels, all_sum, pos_sum);

    finalize_kernel<<<1, 1024, 0, stream>>>(all_sum, pos_sum, labels, out);
}

// Round 12
// 183.747 us; speedup vs baseline: 2.9777x; 1.0123x over previous
//
#include <hip/hip_runtime.h>
#include <hip/hip_bf16.h>
#include <cstdint>
#include <cstddef>

// Problem constants (fixed shapes per reference)
#define NROWS 8192
#define DIM   1024
#define BMR 128           // block rows (2 waves x 64)
#define BNC 128           // block cols
#define BK  64            // K depth per iteration; 16 iterations
#define NBLK 2080         // 64*65/2 triangle tiles = 8 XCDs x 260
#define EPS 1e-8f
// E pre-scaled by sqrt(10*log2(e)) so MFMA accumulates 10*log2(e)*<a,b>;
// epilogue is a bare exp2f.
#define PRESCALE 3.798288f

typedef short  bf16x8  __attribute__((ext_vector_type(8)));
typedef float  floatx4 __attribute__((ext_vector_type(4)));

typedef __attribute__((address_space(1))) const void CGV;
typedef __attribute__((address_space(3))) void LV;

__device__ __forceinline__ void async_load16(const void* g, void* l) {
    __builtin_amdgcn_global_load_lds((CGV*)g, (LV*)l, 16, 0, 0);
}

__device__ __forceinline__ unsigned short f2bf_rne(float f) {
    union { float f; unsigned u; } c; c.f = f;
    unsigned u = c.u;
    unsigned r = (u + 0x7fffu + ((u >> 16) & 1u)) >> 16;
    return (unsigned short)r;
}

// ---------------------------------------------------------------------------
// Kernel A: fp32 -> bf16 (RNE) with PRESCALE folded in. First 64 blocks also
// zero the 16384-float accumulator region.
// ---------------------------------------------------------------------------
__global__ __launch_bounds__(256) void convert_kernel(
    const float* __restrict__ in, unsigned short* __restrict__ out,
    float* __restrict__ accum /* all_sum ++ pos_sum, 2*NROWS floats */)
{
    int i = (blockIdx.x * 256 + threadIdx.x) * 4;
    float4 v = *(const float4*)(in + i);
    ushort4 o;
    o.x = f2bf_rne(v.x * PRESCALE);
    o.y = f2bf_rne(v.y * PRESCALE);
    o.z = f2bf_rne(v.z * PRESCALE);
    o.w = f2bf_rne(v.w * PRESCALE);
    *(ushort4*)(out + i) = o;
    if (blockIdx.x < (2 * NROWS) / 256)
        accum[blockIdx.x * 256 + threadIdx.x] = 0.0f;
}

// ---------------------------------------------------------------------------
// Kernel B: symmetric-half fused GEMM — fat wave tiles (64x128, R11-proven) in
// SMALL 2-wave blocks for 4 independent barrier domains per CU.
// Evidence: R11 (2 blocks/CU, 4-wave blocks) showed every pipe at ~20% with
// occupancy 17% — phase serialization, not bandwidth. 128-thread blocks keep
// the fat tile's DS-bytes/MFMA (0.375 KB) while doubling the number of
// independently-draining barrier groups per CU (4 blocks x 2 waves; regs
// 224/wave -> 2 waves/SIMD; LDS 32 KB x 4 = 128 KB).
// UNIFORM symmetry (R11-verified, absmax 0): keep strictly-lower elements
// (grow > gcol); each feeds row grow AND col gcol — every unordered pair
// exactly once, diag handled implicitly.
// K-loop: R3-proven global_load_lds w16 + 2 __syncthreads; chunk swizzle
// c' = c ^ (row&7) (0 conflicts measured R3/R9/R11). XCD-local tile order.
// ---------------------------------------------------------------------------
__global__ __launch_bounds__(128, 2) void gemm_fused_kernel(
    const unsigned short* __restrict__ E,   // bf16 bits (prescaled), [NROWS][DIM]
    const int*            __restrict__ labels,
    float*                __restrict__ all_sum,
    float*                __restrict__ pos_sum)
{
    __shared__ __align__(16) unsigned short sA[BMR * BK];   // 16 KB
    __shared__ __align__(16) unsigned short sB[BNC * BK];   // 16 KB

    const int tid  = threadIdx.x;
    const int lane = tid & 63;
    const int w    = tid >> 6;      // wave 0/1 -> rows w*64..w*64+63 of block
    const int colw = lane & 15;
    const int quad = lane >> 4;

    // XCD-local linear tile id, then sqrt triangle decode (strips of 128).
    const int b = blockIdx.x;
    const int t = (b & 7) * 260 + (b >> 3);     // 2080 = 8 x 260
    int bi = (int)((sqrtf(8.0f * (float)t + 1.0f) - 1.0f) * 0.5f);
    while ((bi + 1) * (bi + 2) / 2 <= t) ++bi;
    while (bi * (bi + 1) / 2 > t) --bi;
    const int bj = t - bi * (bi + 1) / 2;

    const int rBase = bi * BMR;     // rows (A tile)
    const int cBase = bj * BNC;     // cols (B tile)

    // Staging: each tile = 128x64 elems = 1024 chunks of 16B; 128 threads x
    // 8 chunks each (rows srow + 16j). Swizzled placement: global chunk
    // c = (t&7) ^ (srow&7); srow&7 invariant under +16.
    const int srow = tid >> 3;                          // 0..15
    const int scol = (((tid & 7) ^ (srow & 7)) << 3);   // elem col 0..56
    const int e0   = tid * 8;                           // LDS elem offset/pass

    floatx4 acc[4][8];
    #pragma unroll
    for (int i = 0; i < 4; ++i)
        #pragma unroll
        for (int j = 0; j < 8; ++j)
            acc[i][j] = (floatx4)0.0f;

    // Fragment reads: A row = w*64 + mt*16 + colw; B row = nt*16 + colw.
    // Chunk (h*4+quad) stored at slot ^(row&7) = ^(colw&7).
    const int swz   = colw & 7;
    const int aRow0 = (w * 64 + colw) * BK;
    const int bRow0 = colw * BK;

    const size_t gA0 = (size_t)(rBase + srow) * DIM + scol;
    const size_t gB0 = (size_t)(cBase + srow) * DIM + scol;
    const size_t rstep = (size_t)16 * DIM;

    for (int k0 = 0; k0 < DIM; k0 += BK) {
        __syncthreads();   // previous compute done before overwrite
        #pragma unroll
        for (int j = 0; j < 8; ++j)
            async_load16(E + gA0 + j * rstep + k0, &sA[e0 + j * 1024]);
        #pragma unroll
        for (int j = 0; j < 8; ++j)
            async_load16(E + gB0 + j * rstep + k0, &sB[e0 + j * 1024]);
        __syncthreads();   // vmcnt drained by compiler before barrier

        #pragma unroll
        for (int h = 0; h < 2; ++h) {
            const int cOff = (((h << 2) | quad) ^ swz) << 3;
            bf16x8 aF[4], bF[8];
            #pragma unroll
            for (int mt = 0; mt < 4; ++mt)
                aF[mt] = *(const bf16x8*)&sA[aRow0 + mt * 16 * BK + cOff];
            #pragma unroll
            for (int nt = 0; nt < 8; ++nt)
                bF[nt] = *(const bf16x8*)&sB[bRow0 + nt * 16 * BK + cOff];

            #pragma unroll
            for (int mt = 0; mt < 4; ++mt)
                #pragma unroll
                for (int nt = 0; nt < 8; ++nt)
                    acc[mt][nt] = __builtin_amdgcn_mfma_f32_16x16x32_bf16(
                        aF[mt], bF[nt], acc[mt][nt], 0, 0, 0);
        }
    }

    // Epilogue. C/D layout (16x16x32): col = lane&15, row = quad*4 + reg.
    // Uniform rule: element (grow, gcol) counts iff grow > gcol; contributes
    // to row grow AND col gcol (R11-verified).
    float labc[8];
    int   gcol[8];
    #pragma unroll
    for (int nt = 0; nt < 8; ++nt) {
        gcol[nt] = cBase + nt * 16 + colw;
        labc[nt] = (float)labels[gcol[nt]];
    }

    float colAll[8] = {0.f, 0.f, 0.f, 0.f, 0.f, 0.f, 0.f, 0.f};
    float colPos[8] = {0.f, 0.f, 0.f, 0.f, 0.f, 0.f, 0.f, 0.f};

    #pragma unroll
    for (int mt = 0; mt < 4; ++mt) {
        const int growBase = rBase + w * 64 + mt * 16 + quad * 4;
        #pragma unroll
        for (int r = 0; r < 4; ++r) {
            const int grow = growBase + r;
            const float labr = (float)labels[grow];
            float sAll = 0.f, sPos = 0.f;
            #pragma unroll
            for (int nt = 0; nt < 8; ++nt) {
                float ev = exp2f(acc[mt][nt][r]);   // PRESCALE folded into E
                ev = (grow > gcol[nt]) ? ev : 0.0f; // strictly-lower only
                sAll += ev;
                sPos += ev * labc[nt];
                colAll[nt] += ev;
                colPos[nt] += ev * labr;
            }
            // row-reduce across the 16 lanes (same quad) sharing this row
            #pragma unroll
            for (int off = 1; off < 16; off <<= 1) {
                sAll += __shfl_xor(sAll, off);
                sPos += __shfl_xor(sPos, off);
            }
            if (colw == 0 && sAll != 0.f) {
                atomicAdd(&all_sum[grow], sAll);
                atomicAdd(&pos_sum[grow], sPos);
            }
        }
    }

    // col-reduce: sum across quads (lanes differing in bits 4,5)
    #pragma unroll
    for (int nt = 0; nt < 8; ++nt) {
        float a = colAll[nt], p = colPos[nt];
        a += __shfl_xor(a, 16);  p += __shfl_xor(p, 16);
        a += __shfl_xor(a, 32);  p += __shfl_xor(p, 32);
        if (quad == 0 && a != 0.f) {
            atomicAdd(&all_sum[gcol[nt]], a);
            atomicAdd(&pos_sum[gcol[nt]], p);
        }
    }
}

// ---------------------------------------------------------------------------
// Kernel C: loss = mean over rows with lab==1 of -log(pos/(all+eps)); 0 if n_ref<2
// ---------------------------------------------------------------------------
__global__ __launch_bounds__(1024) void finalize_kernel(
    const float* __restrict__ all_sum,
    const float* __restrict__ pos_sum,
    const int*   __restrict__ labels,
    float*       __restrict__ out)
{
    __shared__ float sSum[1024];
    __shared__ float sCnt[1024];
    const int tid = threadIdx.x;
    float lsum = 0.f, lcnt = 0.f;
    for (int i = tid; i < NROWS; i += 1024) {
        if (labels[i] > 0) {
            float p = pos_sum[i];
            float a = all_sum[i] + EPS;
            lsum += -logf(p / a);
            lcnt += 1.0f;
        }
    }
    sSum[tid] = lsum;
    sCnt[tid] = lcnt;
    __syncthreads();
    for (int s = 512; s > 0; s >>= 1) {
        if (tid < s) { sSum[tid] += sSum[tid + s]; sCnt[tid] += sCnt[tid + s]; }
        __syncthreads();
    }
    if (tid == 0) {
        float n = sCnt[0];
        out[0] = (n < 2.0f) ? 0.0f : sSum[0] / fmaxf(n, 1.0f);
    }
}

// ---------------------------------------------------------------------------
extern "C" void kernel_launch(void* const* d_in, const int* in_sizes, int n_in,
                              void* d_out, int out_size, void* d_ws, size_t ws_size,
                              hipStream_t stream) {
    const float* emb    = (const float*)d_in[0];
    const int*   labels = (const int*)d_in[1];
    float*       out    = (float*)d_out;

    // workspace layout: [bf16 E: 16 MB][all_sum: 32 KB][pos_sum: 32 KB]
    unsigned short* Ebf = (unsigned short*)d_ws;
    const size_t embBytes = (size_t)NROWS * DIM * sizeof(unsigned short);
    float* all_sum = (float*)((char*)d_ws + embBytes);
    float* pos_sum = all_sum + NROWS;

    convert_kernel<<<(NROWS * DIM) / (4 * 256), 256, 0, stream>>>(emb, Ebf, all_sum);

    gemm_fused_kernel<<<NBLK, 128, 0, stream>>>(Ebf, labels, all_sum, pos_sum);

    finalize_kernel<<<1, 1024, 0, stream>>>(all_sum, pos_sum, labels, out);
}